// Round 2
// baseline (602.851 us; speedup 1.0000x reference)
//
#include <hip/hip_runtime.h>
#include <hip/hip_bf16.h>
#include <stdint.h>

#define DIM 2048
#define NEXP 8
#define NTOK 8192
#define KSEL 6
#define NPAIR 28
#define SLOTS 92   // max sum of ceil(cnt_p/128) = 64 + 27, +1 safety

typedef short bf16x8 __attribute__((ext_vector_type(8)));
typedef unsigned short u16x8 __attribute__((ext_vector_type(8)));
typedef float f32x4 __attribute__((ext_vector_type(4)));
typedef const __attribute__((address_space(1))) unsigned int GU32;
typedef __attribute__((address_space(3))) unsigned int LU32;

// pair id p <-> (a,b), a<b: p = a*(15-a)/2 + (b-a-1)
static constexpr int PA[NPAIR] = {0,0,0,0,0,0,0,1,1,1,1,1,1,2,2,2,2,2,3,3,3,3,4,4,4,5,5,6};
static constexpr int PB[NPAIR] = {1,2,3,4,5,6,7,2,3,4,5,6,7,3,4,5,6,7,4,5,6,7,5,6,7,6,7,7};

__device__ __forceinline__ unsigned short f2b(float f) {
  union { float f; uint32_t u; } v; v.f = f;
  return (unsigned short)((v.u + 0x7fffu + ((v.u >> 16) & 1u)) >> 16);
}

__global__ void zero_cnt_kernel(int* cnt) {
  if (threadIdx.x < NPAIR) cnt[threadIdx.x] = 0;
}

// One wave per token: fp32 gate scores (exact top-k w/ jax tie-break),
// write bf16 cast of x and the excluded-PAIR id. No atomics.
__global__ __launch_bounds__(256) void gate_kernel(
    const float* __restrict__ x, const float* __restrict__ Wg,
    const float* __restrict__ bg, unsigned short* __restrict__ xB,
    int* __restrict__ pid) {
  int t = threadIdx.x;
  int w = t >> 6, l = t & 63;
  int n = blockIdx.x * 4 + w;
  const float* xr = x + (size_t)n * DIM;
  float xv[32];
#pragma unroll
  for (int j = 0; j < 8; ++j) {
    float4 v = *(const float4*)(xr + 4 * l + 256 * j);
    xv[4 * j + 0] = v.x; xv[4 * j + 1] = v.y;
    xv[4 * j + 2] = v.z; xv[4 * j + 3] = v.w;
  }
  unsigned short* xbr = xB + (size_t)n * DIM;
#pragma unroll
  for (int j = 0; j < 8; ++j) {
    ushort4 o;
    o.x = f2b(xv[4 * j + 0]); o.y = f2b(xv[4 * j + 1]);
    o.z = f2b(xv[4 * j + 2]); o.w = f2b(xv[4 * j + 3]);
    *(ushort4*)(xbr + 4 * l + 256 * j) = o;
  }
  float sc[NEXP];
#pragma unroll
  for (int e = 0; e < NEXP; ++e) {
    const float* wr = Wg + e * DIM;
    float s = 0.f;
#pragma unroll
    for (int j = 0; j < 8; ++j) {
      float4 v = *(const float4*)(wr + 4 * l + 256 * j);
      s += xv[4 * j + 0] * v.x + xv[4 * j + 1] * v.y +
           xv[4 * j + 2] * v.z + xv[4 * j + 3] * v.w;
    }
#pragma unroll
    for (int off = 32; off > 0; off >>= 1) s += __shfl_xor(s, off, 64);
    sc[e] = s + bg[e];
  }
  if (l == 0) {
    int ex0 = -1, ex1 = -1;
#pragma unroll
    for (int e = 0; e < NEXP; ++e) {
      int rank = 0;
#pragma unroll
      for (int j = 0; j < NEXP; ++j)
        rank += (sc[j] > sc[e]) || (sc[j] == sc[e] && j < e);
      if (rank >= KSEL) { if (ex0 < 0) ex0 = e; else if (ex1 < 0) ex1 = e; }
    }
    pid[n] = ex0 * (15 - ex0) / 2 + (ex1 - ex0 - 1);
  }
}

// Two-phase bucketing: LDS histogram per block (2048 tokens), ONE global
// atomic per pair per block (4*28 = 112 total), then scatter.
__global__ __launch_bounds__(256) void bucket_kernel(
    const int* __restrict__ pid, int* __restrict__ cnt, int* __restrict__ list) {
  __shared__ int lcnt[NPAIR];
  __shared__ int gbase[NPAIR];
  int t = threadIdx.x;
  if (t < NPAIR) lcnt[t] = 0;
  __syncthreads();
  int base = blockIdx.x * 2048;
  int p[8], lp[8];
#pragma unroll
  for (int j = 0; j < 8; ++j) {
    int n = base + t + 256 * j;
    p[j] = pid[n];
    lp[j] = atomicAdd(&lcnt[p[j]], 1);
  }
  __syncthreads();
  if (t < NPAIR) gbase[t] = atomicAdd(&cnt[t], lcnt[t]);
  __syncthreads();
#pragma unroll
  for (int j = 0; j < 8; ++j) {
    int n = base + t + 256 * j;
    list[p[j] * NTOK + gbase[p[j]] + lp[j]] = n;
  }
}

// Prefix-sum of per-pair 128-row tile counts -> tile slot table.
__global__ void tilemap_kernel(const int* __restrict__ cnt, int* __restrict__ tileBase) {
  if (threadIdx.x == 0) {
    int s = 0;
    for (int p = 0; p < NPAIR; ++p) { tileBase[p] = s; s += (cnt[p] + 127) >> 7; }
    tileBase[NPAIR] = s;
  }
}

// biasPair[p][f] = sum_e be[e][f] - be[a][f] - be[b][f]
__global__ __launch_bounds__(256) void biaspair_kernel(
    const float* __restrict__ be, float* __restrict__ biasPair) {
  int f = blockIdx.x * 256 + threadIdx.x;
  float v[NEXP]; float s = 0.f;
#pragma unroll
  for (int e = 0; e < NEXP; ++e) { v[e] = be[e * DIM + f]; s += v[e]; }
#pragma unroll
  for (int pp = 0; pp < NPAIR; ++pp)
    biasPair[pp * DIM + f] = s - v[PA[pp]] - v[PB[pp]];
}

// Wsumf[f][d] = sum_e We[e][f][d] in fp32 (exact, same accumulation order as
// the old pairw). One streaming pass: read We 134 MB, write 16 MB.
__global__ __launch_bounds__(256) void wsum_kernel(
    const float* __restrict__ We, float* __restrict__ Wsumf) {
  size_t p = ((size_t)blockIdx.x * 256 + threadIdx.x) * 4;
  float sx = 0.f, sy = 0.f, sz = 0.f, sw = 0.f;
#pragma unroll
  for (int e = 0; e < NEXP; ++e) {
    float4 v = *(const float4*)(We + (size_t)e * DIM * DIM + p);
    sx += v.x; sy += v.y; sz += v.z; sw += v.w;
  }
  float4 o; o.x = sx; o.y = sy; o.z = sz; o.w = sw;
  *(float4*)(Wsumf + p) = o;
}

// Pair-bucket GEMM with on-the-fly B construction:
//   B[f][k] = bf16( Wsumf[f][k] - We[a][f][k] - We[b][f][k] )   (fp32 subtract,
// single bf16 round -> numerically identical to the old materialized Wpair).
// A staged via global_load_lds w=16 (unchanged). B reg-staged: the ds_write
// mirrors the DMA's lane->LDS mapping (stripe base + l*16B), so the swizzled
// ds_read side is untouched. Each out element written exactly once, bias fused.
__global__ __launch_bounds__(256, 3) void gemm_pair(
    const unsigned short* __restrict__ A, const float* __restrict__ Wsumf,
    const float* __restrict__ We,
    const int* __restrict__ cnt, const int* __restrict__ list,
    const int* __restrict__ tileBase, const float* __restrict__ biasPair,
    float* __restrict__ out) {
  __shared__ unsigned short sA[128 * 64];
  __shared__ unsigned short sB[128 * 64];
  __shared__ int sRows[128];
  int slot = blockIdx.y, ft = blockIdx.x;
  if (slot >= tileBase[NPAIR]) return;
  int p = 0;
  while (p + 1 < NPAIR && tileBase[p + 1] <= slot) ++p;
  int c = cnt[p];
  int m0 = (slot - tileBase[p]) * 128;
  if (m0 >= c) return;
  // p -> (a,b)
  int pv = p, a = 0;
  while (pv >= 7 - a) { pv -= 7 - a; ++a; }
  int b = a + 1 + pv;
  const float* Wea = We + (size_t)a * DIM * DIM;
  const float* Web = We + (size_t)b * DIM * DIM;

  int t = threadIdx.x;
  int w = t >> 6, l = t & 63;
  int wm = w & 1, wn = w >> 1;
  int quad = l >> 4, lr = l & 15;
  int cs = (l & 7) ^ ((l >> 3) & 7);   // staging k-granule for this lane

  if (t < 128) {
    int idx = m0 + t;
    if (idx >= c) idx = c - 1;
    sRows[t] = list[p * NTOK + idx];
  }
  __syncthreads();

  size_t rowOffA[4], bOff[4];
  int ldsRow[4];
#pragma unroll
  for (int i = 0; i < 4; ++i) {
    rowOffA[i] = (size_t)sRows[i * 32 + w * 8 + (l >> 3)] * DIM;
    bOff[i] = (size_t)(ft * 128 + i * 32 + w * 8 + (l >> 3)) * DIM + cs * 8;
    ldsRow[i] = (i * 32 + w * 8) * 64 + l * 8;  // == DMA's base + l*16B (ushorts)
  }

  f32x4 acc[4][4];
#pragma unroll
  for (int mi = 0; mi < 4; ++mi)
#pragma unroll
    for (int ni = 0; ni < 4; ++ni) {
      acc[mi][ni][0] = 0.f; acc[mi][ni][1] = 0.f;
      acc[mi][ni][2] = 0.f; acc[mi][ni][3] = 0.f;
    }

  for (int k0 = 0; k0 < DIM; k0 += 64) {
    // A: async DMA into LDS (4 x 16B per thread)
#pragma unroll
    for (int i = 0; i < 4; ++i)
      __builtin_amdgcn_global_load_lds((GU32*)(A + rowOffA[i] + k0 + cs * 8),
          (LU32*)(sA + (i * 32 + w * 8) * 64), 16, 0, 0);
    // B: reg-stage 8 elems per row-group: fp32 subtract, one bf16 round
#pragma unroll
    for (int i = 0; i < 4; ++i) {
      const float* pS = Wsumf + bOff[i] + k0;
      const float* pa = Wea + bOff[i] + k0;
      const float* pb = Web + bOff[i] + k0;
      float4 s0 = *(const float4*)(pS);     float4 s1 = *(const float4*)(pS + 4);
      float4 a0 = *(const float4*)(pa);     float4 a1 = *(const float4*)(pa + 4);
      float4 b0 = *(const float4*)(pb);     float4 b1 = *(const float4*)(pb + 4);
      u16x8 v;
      v[0] = f2b(s0.x - a0.x - b0.x); v[1] = f2b(s0.y - a0.y - b0.y);
      v[2] = f2b(s0.z - a0.z - b0.z); v[3] = f2b(s0.w - a0.w - b0.w);
      v[4] = f2b(s1.x - a1.x - b1.x); v[5] = f2b(s1.y - a1.y - b1.y);
      v[6] = f2b(s1.z - a1.z - b1.z); v[7] = f2b(s1.w - a1.w - b1.w);
      *(u16x8*)(sB + ldsRow[i]) = v;
    }
    __syncthreads();
#pragma unroll
    for (int ks = 0; ks < 2; ++ks) {
      bf16x8 aF[4], bF[4];
#pragma unroll
      for (int mi = 0; mi < 4; ++mi)
        aF[mi] = *(const bf16x8*)(sA + (wm * 64 + mi * 16 + lr) * 64 +
                                  (((ks << 2) | quad) ^ (lr & 7)) * 8);
#pragma unroll
      for (int ni = 0; ni < 4; ++ni)
        bF[ni] = *(const bf16x8*)(sB + (wn * 64 + ni * 16 + lr) * 64 +
                                  (((ks << 2) | quad) ^ (lr & 7)) * 8);
#pragma unroll
      for (int mi = 0; mi < 4; ++mi)
#pragma unroll
        for (int ni = 0; ni < 4; ++ni)
          acc[mi][ni] = __builtin_amdgcn_mfma_f32_16x16x32_bf16(aF[mi], bF[ni], acc[mi][ni], 0, 0, 0);
    }
    __syncthreads();
  }

  int f0 = ft * 128;
  float bb[4];
#pragma unroll
  for (int ni = 0; ni < 4; ++ni)
    bb[ni] = biasPair[p * DIM + f0 + wn * 64 + ni * 16 + lr];
#pragma unroll
  for (int mi = 0; mi < 4; ++mi) {
#pragma unroll
    for (int i = 0; i < 4; ++i) {
      int lrow = wm * 64 + mi * 16 + quad * 4 + i;
      if (m0 + lrow < c) {
        float* orow = out + (size_t)sRows[lrow] * DIM + f0;
#pragma unroll
        for (int ni = 0; ni < 4; ++ni)
          orow[wn * 64 + ni * 16 + lr] = acc[mi][ni][i] + bb[ni];
      }
    }
  }
}

extern "C" void kernel_launch(void* const* d_in, const int* in_sizes, int n_in,
                              void* d_out, int out_size, void* d_ws, size_t ws_size,
                              hipStream_t stream) {
  const float* x  = (const float*)d_in[0];
  const float* Wg = (const float*)d_in[1];
  const float* bg = (const float*)d_in[2];
  const float* We = (const float*)d_in[3];
  const float* be = (const float*)d_in[4];
  float* out = (float*)d_out;

  char* ws = (char*)d_ws;
  unsigned short* xB = (unsigned short*)ws; ws += (size_t)NTOK * DIM * 2;
  int* pid = (int*)ws;          ws += (size_t)NTOK * 4;
  int* cnt = (int*)ws;          ws += 128;
  int* tileBase = (int*)ws;     ws += 128;
  int* list = (int*)ws;         ws += (size_t)NPAIR * NTOK * 4;
  float* biasPair = (float*)ws; ws += (size_t)NPAIR * DIM * 4;
  float* Wsumf = (float*)ws;    ws += (size_t)DIM * DIM * 4;

  zero_cnt_kernel<<<1, 64, 0, stream>>>(cnt);
  gate_kernel<<<NTOK / 4, 256, 0, stream>>>(x, Wg, bg, xB, pid);
  bucket_kernel<<<4, 256, 0, stream>>>(pid, cnt, list);
  tilemap_kernel<<<1, 64, 0, stream>>>(cnt, tileBase);
  biaspair_kernel<<<DIM / 256, 256, 0, stream>>>(be, biasPair);
  wsum_kernel<<<(DIM * DIM) / 1024, 256, 0, stream>>>(We, Wsumf);
  gemm_pair<<<dim3(DIM / 128, SLOTS), 256, 0, stream>>>(
      xB, Wsumf, We, cnt, list, tileBase, biasPair, out);
}

// Round 3
// 471.509 us; speedup vs baseline: 1.2786x; 1.2786x over previous
//
#include <hip/hip_runtime.h>
#include <hip/hip_bf16.h>
#include <stdint.h>

#define DIM 2048
#define NEXP 8
#define NTOK 8192
#define KSEL 6
#define NPAIR 28
#define SLOTS 92   // max sum of ceil(cnt_p/128) = 64 + 27, +1 safety

typedef short bf16x8 __attribute__((ext_vector_type(8)));
typedef unsigned short u16x8 __attribute__((ext_vector_type(8)));
typedef float f32x4 __attribute__((ext_vector_type(4)));
typedef const __attribute__((address_space(1))) unsigned int GU32;
typedef __attribute__((address_space(3))) unsigned int LU32;

// pair id p <-> (a,b), a<b: p = a*(15-a)/2 + (b-a-1)
static constexpr int PA[NPAIR] = {0,0,0,0,0,0,0,1,1,1,1,1,1,2,2,2,2,2,3,3,3,3,4,4,4,5,5,6};
static constexpr int PB[NPAIR] = {1,2,3,4,5,6,7,2,3,4,5,6,7,3,4,5,6,7,4,5,6,7,5,6,7,6,7,7};

__device__ __forceinline__ unsigned short f2b(float f) {
  union { float f; uint32_t u; } v; v.f = f;
  return (unsigned short)((v.u + 0x7fffu + ((v.u >> 16) & 1u)) >> 16);
}

// One wave per token: fp32 gate scores (exact top-k w/ jax tie-break),
// write bf16 cast of x and the excluded-PAIR id. No atomics.
__global__ __launch_bounds__(256) void gate_kernel(
    const float* __restrict__ x, const float* __restrict__ Wg,
    const float* __restrict__ bg, unsigned short* __restrict__ xB,
    int* __restrict__ pid) {
  int t = threadIdx.x;
  int w = t >> 6, l = t & 63;
  int n = blockIdx.x * 4 + w;
  const float* xr = x + (size_t)n * DIM;
  float xv[32];
#pragma unroll
  for (int j = 0; j < 8; ++j) {
    float4 v = *(const float4*)(xr + 4 * l + 256 * j);
    xv[4 * j + 0] = v.x; xv[4 * j + 1] = v.y;
    xv[4 * j + 2] = v.z; xv[4 * j + 3] = v.w;
  }
  unsigned short* xbr = xB + (size_t)n * DIM;
#pragma unroll
  for (int j = 0; j < 8; ++j) {
    ushort4 o;
    o.x = f2b(xv[4 * j + 0]); o.y = f2b(xv[4 * j + 1]);
    o.z = f2b(xv[4 * j + 2]); o.w = f2b(xv[4 * j + 3]);
    *(ushort4*)(xbr + 4 * l + 256 * j) = o;
  }
  float sc[NEXP];
#pragma unroll
  for (int e = 0; e < NEXP; ++e) {
    const float* wr = Wg + e * DIM;
    float s = 0.f;
#pragma unroll
    for (int j = 0; j < 8; ++j) {
      float4 v = *(const float4*)(wr + 4 * l + 256 * j);
      s += xv[4 * j + 0] * v.x + xv[4 * j + 1] * v.y +
           xv[4 * j + 2] * v.z + xv[4 * j + 3] * v.w;
    }
#pragma unroll
    for (int off = 32; off > 0; off >>= 1) s += __shfl_xor(s, off, 64);
    sc[e] = s + bg[e];
  }
  if (l == 0) {
    int ex0 = -1, ex1 = -1;
#pragma unroll
    for (int e = 0; e < NEXP; ++e) {
      int rank = 0;
#pragma unroll
      for (int j = 0; j < NEXP; ++j)
        rank += (sc[j] > sc[e]) || (sc[j] == sc[e] && j < e);
      if (rank >= KSEL) { if (ex0 < 0) ex0 = e; else if (ex1 < 0) ex1 = e; }
    }
    pid[n] = ex0 * (15 - ex0) / 2 + (ex1 - ex0 - 1);
  }
}

// Single block: histogram (LDS atomics) -> prefix -> scatter. Replaces
// zero_cnt + bucket + tilemap; no global atomics anywhere.
__global__ __launch_bounds__(1024) void bucket_all(
    const int* __restrict__ pid, int* __restrict__ cnt,
    int* __restrict__ tileBase, int* __restrict__ list) {
  __shared__ int lcnt[NPAIR];
  __shared__ int lpos[NPAIR];
  __shared__ int lbase[NPAIR];
  int t = threadIdx.x;
  if (t < NPAIR) { lcnt[t] = 0; lpos[t] = 0; }
  __syncthreads();
  int p[8];
#pragma unroll
  for (int j = 0; j < 8; ++j) {
    p[j] = pid[t + 1024 * j];
    atomicAdd(&lcnt[p[j]], 1);
  }
  __syncthreads();
  if (t == 0) {
    int s = 0, ts = 0;
    for (int q = 0; q < NPAIR; ++q) {
      lbase[q] = s; s += lcnt[q];
      cnt[q] = lcnt[q];
      tileBase[q] = ts; ts += (lcnt[q] + 127) >> 7;
    }
    tileBase[NPAIR] = ts;
  }
  __syncthreads();
#pragma unroll
  for (int j = 0; j < 8; ++j) {
    int pos = atomicAdd(&lpos[p[j]], 1);
    list[p[j] * NTOK + lbase[p[j]] + pos - lbase[p[j]] + 0] = 0; // placeholder avoided below
  }
}

// NOTE: bucket_all above must write list correctly; simpler correct version:
__global__ __launch_bounds__(1024) void bucket_all2(
    const int* __restrict__ pid, int* __restrict__ cnt,
    int* __restrict__ tileBase, int* __restrict__ list) {
  __shared__ int lcnt[NPAIR];
  __shared__ int lpos[NPAIR];
  int t = threadIdx.x;
  if (t < NPAIR) { lcnt[t] = 0; lpos[t] = 0; }
  __syncthreads();
  int p[8];
#pragma unroll
  for (int j = 0; j < 8; ++j) {
    p[j] = pid[t + 1024 * j];
    atomicAdd(&lcnt[p[j]], 1);
  }
  __syncthreads();
  if (t == 0) {
    int ts = 0;
    for (int q = 0; q < NPAIR; ++q) {
      cnt[q] = lcnt[q];
      tileBase[q] = ts; ts += (lcnt[q] + 127) >> 7;
    }
    tileBase[NPAIR] = ts;
  }
  __syncthreads();
#pragma unroll
  for (int j = 0; j < 8; ++j) {
    int pos = atomicAdd(&lpos[p[j]], 1);
    list[p[j] * NTOK + pos] = t + 1024 * j;
  }
}

// biasPair[p][f] = sum_e be[e][f] - be[a][f] - be[b][f]
__global__ __launch_bounds__(256) void biaspair_kernel(
    const float* __restrict__ be, float* __restrict__ biasPair) {
  int f = blockIdx.x * 256 + threadIdx.x;
  float v[NEXP]; float s = 0.f;
#pragma unroll
  for (int e = 0; e < NEXP; ++e) { v[e] = be[e * DIM + f]; s += v[e]; }
#pragma unroll
  for (int pp = 0; pp < NPAIR; ++pp)
    biasPair[pp * DIM + f] = s - v[PA[pp]] - v[PB[pp]];
}

// Wpair[p] = bf16(sum_e We[e] - We[a] - We[b]) for f-rows [fbase, fbase+frows).
// One streaming pass over We; 8 positions/thread so pair-stream stores are
// 16 B/lane (fewer, bigger bursts than r1's 8 B).
__global__ __launch_bounds__(256) void pairw_kernel(
    const float* __restrict__ We, unsigned short* __restrict__ Wp,
    int fbase, int frows) {
  size_t pos = ((size_t)blockIdx.x * 256 + threadIdx.x) * 8;
  size_t src = (size_t)fbase * DIM + pos;
  float v[NEXP][8];
  float s[8];
#pragma unroll
  for (int i = 0; i < 8; ++i) s[i] = 0.f;
#pragma unroll
  for (int e = 0; e < NEXP; ++e) {
    float4 v0 = *(const float4*)(We + (size_t)e * DIM * DIM + src);
    float4 v1 = *(const float4*)(We + (size_t)e * DIM * DIM + src + 4);
    v[e][0] = v0.x; v[e][1] = v0.y; v[e][2] = v0.z; v[e][3] = v0.w;
    v[e][4] = v1.x; v[e][5] = v1.y; v[e][6] = v1.z; v[e][7] = v1.w;
#pragma unroll
    for (int i = 0; i < 8; ++i) s[i] += v[e][i];
  }
  size_t chunk = (size_t)frows * DIM;
#pragma unroll
  for (int pp = 0; pp < NPAIR; ++pp) {
    int a = PA[pp], b = PB[pp];
    u16x8 o;
#pragma unroll
    for (int i = 0; i < 8; ++i) o[i] = f2b(s[i] - v[a][i] - v[b][i]);
    *(u16x8*)(Wp + (size_t)pp * chunk + pos) = o;
  }
}

// Pair-bucket GEMM (r1 structure): out rows = gathered x . Wpair[p]^T + biasPair.
// 128x128 tile, BK=64, 16x16x32 bf16 MFMA, global_load_lds w=16, XOR swizzle.
// Slot order REVERSED so the gemm consumes the freshest (LLC-resident) Wpair
// pages first. 4 blocks/CU.
__global__ __launch_bounds__(256, 4) void gemm_pair(
    const unsigned short* __restrict__ A, const unsigned short* __restrict__ Wp,
    const int* __restrict__ cnt, const int* __restrict__ list,
    const int* __restrict__ tileBase, const float* __restrict__ biasPair,
    float* __restrict__ out, int fbase, int frows) {
  __shared__ unsigned short sA[128 * 64];
  __shared__ unsigned short sB[128 * 64];
  __shared__ int sRows[128];
  int total = tileBase[NPAIR];
  if (blockIdx.y >= total) return;
  int slot = total - 1 - blockIdx.y;   // reversed for LLC freshness
  int ft = blockIdx.x;
  int p = 0;
  while (p + 1 < NPAIR && tileBase[p + 1] <= slot) ++p;
  int c = cnt[p];
  int m0 = (slot - tileBase[p]) * 128;

  int t = threadIdx.x;
  int w = t >> 6, l = t & 63;
  int wm = w & 1, wn = w >> 1;
  int quad = l >> 4, lr = l & 15;
  int cs = (l & 7) ^ ((l >> 3) & 7);

  if (t < 128) {
    int idx = m0 + t;
    if (idx >= c) idx = c - 1;
    sRows[t] = list[p * NTOK + idx];
  }
  __syncthreads();

  size_t rowOffA[4], rowOffB[4];
#pragma unroll
  for (int i = 0; i < 4; ++i)
    rowOffA[i] = (size_t)sRows[i * 32 + w * 8 + (l >> 3)] * DIM;
  const unsigned short* Bb =
      Wp + (size_t)p * frows * DIM + (size_t)ft * 128 * DIM;
#pragma unroll
  for (int i = 0; i < 4; ++i)
    rowOffB[i] = (size_t)(i * 32 + w * 8 + (l >> 3)) * DIM;

  f32x4 acc[4][4];
#pragma unroll
  for (int mi = 0; mi < 4; ++mi)
#pragma unroll
    for (int ni = 0; ni < 4; ++ni) {
      acc[mi][ni][0] = 0.f; acc[mi][ni][1] = 0.f;
      acc[mi][ni][2] = 0.f; acc[mi][ni][3] = 0.f;
    }

  for (int k0 = 0; k0 < DIM; k0 += 64) {
#pragma unroll
    for (int i = 0; i < 4; ++i) {
      __builtin_amdgcn_global_load_lds((GU32*)(A + rowOffA[i] + k0 + cs * 8),
          (LU32*)(sA + (i * 32 + w * 8) * 64), 16, 0, 0);
      __builtin_amdgcn_global_load_lds((GU32*)(Bb + rowOffB[i] + k0 + cs * 8),
          (LU32*)(sB + (i * 32 + w * 8) * 64), 16, 0, 0);
    }
    __syncthreads();
#pragma unroll
    for (int ks = 0; ks < 2; ++ks) {
      bf16x8 aF[4], bF[4];
#pragma unroll
      for (int mi = 0; mi < 4; ++mi)
        aF[mi] = *(const bf16x8*)(sA + (wm * 64 + mi * 16 + lr) * 64 +
                                  (((ks << 2) | quad) ^ (lr & 7)) * 8);
#pragma unroll
      for (int ni = 0; ni < 4; ++ni)
        bF[ni] = *(const bf16x8*)(sB + (wn * 64 + ni * 16 + lr) * 64 +
                                  (((ks << 2) | quad) ^ (lr & 7)) * 8);
#pragma unroll
      for (int mi = 0; mi < 4; ++mi)
#pragma unroll
        for (int ni = 0; ni < 4; ++ni)
          acc[mi][ni] = __builtin_amdgcn_mfma_f32_16x16x32_bf16(aF[mi], bF[ni], acc[mi][ni], 0, 0, 0);
    }
    __syncthreads();
  }

  int f0 = fbase + ft * 128;
  float bb[4];
#pragma unroll
  for (int ni = 0; ni < 4; ++ni)
    bb[ni] = biasPair[p * DIM + f0 + wn * 64 + ni * 16 + lr];
#pragma unroll
  for (int mi = 0; mi < 4; ++mi) {
#pragma unroll
    for (int i = 0; i < 4; ++i) {
      int lrow = wm * 64 + mi * 16 + quad * 4 + i;
      if (m0 + lrow < c) {
        float* orow = out + (size_t)sRows[lrow] * DIM + f0;
#pragma unroll
        for (int ni = 0; ni < 4; ++ni)
          orow[wn * 64 + ni * 16 + lr] = acc[mi][ni][i] + bb[ni];
      }
    }
  }
}

extern "C" void kernel_launch(void* const* d_in, const int* in_sizes, int n_in,
                              void* d_out, int out_size, void* d_ws, size_t ws_size,
                              hipStream_t stream) {
  const float* x  = (const float*)d_in[0];
  const float* Wg = (const float*)d_in[1];
  const float* bg = (const float*)d_in[2];
  const float* We = (const float*)d_in[3];
  const float* be = (const float*)d_in[4];
  float* out = (float*)d_out;

  char* ws = (char*)d_ws;
  unsigned short* xB = (unsigned short*)ws; ws += (size_t)NTOK * DIM * 2;
  int* pid = (int*)ws;          ws += (size_t)NTOK * 4;
  int* cnt = (int*)ws;          ws += 128;
  int* tileBase = (int*)ws;     ws += 128;
  int* list = (int*)ws;         ws += (size_t)NPAIR * NTOK * 4;
  float* biasPair = (float*)ws; ws += (size_t)NPAIR * DIM * 4;
  unsigned short* Wp = (unsigned short*)ws;

  // f-chunking so Wpair fits the workspace: NR rounds of frows = DIM/NR.
  size_t avail = ws_size - (size_t)(ws - (char*)d_ws);
  int NR = 1;
  while (NR < 16 && (size_t)NPAIR * DIM * (size_t)(DIM / NR) * 2 > avail) NR <<= 1;
  int frows = DIM / NR;

  gate_kernel<<<NTOK / 4, 256, 0, stream>>>(x, Wg, bg, xB, pid);
  bucket_all2<<<1, 1024, 0, stream>>>(pid, cnt, tileBase, list);
  biaspair_kernel<<<DIM / 256, 256, 0, stream>>>(be, biasPair);
  for (int r = 0; r < NR; ++r) {
    int fbase = r * frows;
    pairw_kernel<<<(frows * DIM) / 2048, 256, 0, stream>>>(We, Wp, fbase, frows);
    gemm_pair<<<dim3(frows / 128, SLOTS), 256, 0, stream>>>(
        xB, Wp, cnt, list, tileBase, biasPair, out, fbase, frows);
  }
}

// Round 4
// 461.721 us; speedup vs baseline: 1.3057x; 1.0212x over previous
//
#include <hip/hip_runtime.h>
#include <hip/hip_bf16.h>
#include <stdint.h>

#define DIM 2048
#define NEXP 8
#define NTOK 8192
#define KSEL 6
#define NPAIR 28
#define SLOTS 92   // max sum of ceil(cnt_p/128) = 64 + 27, +1 safety

typedef short bf16x8 __attribute__((ext_vector_type(8)));
typedef unsigned short u16x8 __attribute__((ext_vector_type(8)));
typedef float f32x4 __attribute__((ext_vector_type(4)));
typedef const __attribute__((address_space(1))) unsigned int GU32;
typedef __attribute__((address_space(3))) unsigned int LU32;

// pair id p <-> (a,b), a<b: p = a*(15-a)/2 + (b-a-1)
static constexpr int PA[NPAIR] = {0,0,0,0,0,0,0,1,1,1,1,1,1,2,2,2,2,2,3,3,3,3,4,4,4,5,5,6};
static constexpr int PB[NPAIR] = {1,2,3,4,5,6,7,2,3,4,5,6,7,3,4,5,6,7,4,5,6,7,5,6,7,6,7,7};

__device__ __forceinline__ unsigned short f2b(float f) {
  union { float f; uint32_t u; } v; v.f = f;
  return (unsigned short)((v.u + 0x7fffu + ((v.u >> 16) & 1u)) >> 16);
}

// One wave per token: fp32 gate scores (exact top-k w/ jax tie-break),
// write bf16 cast of x and the excluded-PAIR id. No atomics.
__global__ __launch_bounds__(256) void gate_kernel(
    const float* __restrict__ x, const float* __restrict__ Wg,
    const float* __restrict__ bg, unsigned short* __restrict__ xB,
    int* __restrict__ pid) {
  int t = threadIdx.x;
  int w = t >> 6, l = t & 63;
  int n = blockIdx.x * 4 + w;
  const float* xr = x + (size_t)n * DIM;
  float xv[32];
#pragma unroll
  for (int j = 0; j < 8; ++j) {
    float4 v = *(const float4*)(xr + 4 * l + 256 * j);
    xv[4 * j + 0] = v.x; xv[4 * j + 1] = v.y;
    xv[4 * j + 2] = v.z; xv[4 * j + 3] = v.w;
  }
  unsigned short* xbr = xB + (size_t)n * DIM;
#pragma unroll
  for (int j = 0; j < 8; ++j) {
    ushort4 o;
    o.x = f2b(xv[4 * j + 0]); o.y = f2b(xv[4 * j + 1]);
    o.z = f2b(xv[4 * j + 2]); o.w = f2b(xv[4 * j + 3]);
    *(ushort4*)(xbr + 4 * l + 256 * j) = o;
  }
  float sc[NEXP];
#pragma unroll
  for (int e = 0; e < NEXP; ++e) {
    const float* wr = Wg + e * DIM;
    float s = 0.f;
#pragma unroll
    for (int j = 0; j < 8; ++j) {
      float4 v = *(const float4*)(wr + 4 * l + 256 * j);
      s += xv[4 * j + 0] * v.x + xv[4 * j + 1] * v.y +
           xv[4 * j + 2] * v.z + xv[4 * j + 3] * v.w;
    }
#pragma unroll
    for (int off = 32; off > 0; off >>= 1) s += __shfl_xor(s, off, 64);
    sc[e] = s + bg[e];
  }
  if (l == 0) {
    int ex0 = -1, ex1 = -1;
#pragma unroll
    for (int e = 0; e < NEXP; ++e) {
      int rank = 0;
#pragma unroll
      for (int j = 0; j < NEXP; ++j)
        rank += (sc[j] > sc[e]) || (sc[j] == sc[e] && j < e);
      if (rank >= KSEL) { if (ex0 < 0) ex0 = e; else if (ex1 < 0) ex1 = e; }
    }
    pid[n] = ex0 * (15 - ex0) / 2 + (ex1 - ex0 - 1);
  }
}

// Block 0: histogram (LDS atomics) -> cnt + slot->(p,m0) table -> scatter.
// Block 1: biasPair. One launch replaces three.
__global__ __launch_bounds__(1024) void bucket_kernel(
    const int* __restrict__ pid, const float* __restrict__ be,
    int* __restrict__ cnt, int* __restrict__ meta,
    int* __restrict__ slotP, int* __restrict__ slotM0,
    int* __restrict__ list, float* __restrict__ biasPair) {
  int t = threadIdx.x;
  if (blockIdx.x == 1) {
    // biasPair[p][f] = sum_e be[e][f] - be[a][f] - be[b][f]
#pragma unroll
    for (int it = 0; it < 2; ++it) {
      int f = t + 1024 * it;
      float v[NEXP]; float s = 0.f;
#pragma unroll
      for (int e = 0; e < NEXP; ++e) { v[e] = be[e * DIM + f]; s += v[e]; }
#pragma unroll
      for (int pp = 0; pp < NPAIR; ++pp)
        biasPair[pp * DIM + f] = s - v[PA[pp]] - v[PB[pp]];
    }
    return;
  }
  __shared__ int lcnt[NPAIR];
  __shared__ int lpos[NPAIR];
  if (t < NPAIR) { lcnt[t] = 0; lpos[t] = 0; }
  __syncthreads();
  int p[8];
#pragma unroll
  for (int j = 0; j < 8; ++j) {
    p[j] = pid[t + 1024 * j];
    atomicAdd(&lcnt[p[j]], 1);
  }
  __syncthreads();
  if (t == 0) {
    int ts = 0;
    for (int q = 0; q < NPAIR; ++q) {
      cnt[q] = lcnt[q];
      for (int s0 = 0; s0 < lcnt[q]; s0 += 128) {
        slotP[ts] = q; slotM0[ts] = s0; ++ts;
      }
    }
    meta[0] = ts;
  }
  __syncthreads();
#pragma unroll
  for (int j = 0; j < 8; ++j) {
    int pos = atomicAdd(&lpos[p[j]], 1);
    list[p[j] * NTOK + pos] = t + 1024 * j;
  }
}

// Wpair[p] = bf16(sum_e We[e] - We[a] - We[b]) for f-rows [fbase, fbase+frows).
// One streaming pass over We slice; 16 B/lane stores per pair stream.
__global__ __launch_bounds__(256) void pairw_kernel(
    const float* __restrict__ We, unsigned short* __restrict__ Wp,
    int fbase, int frows) {
  size_t pos = ((size_t)blockIdx.x * 256 + threadIdx.x) * 8;
  size_t src = (size_t)fbase * DIM + pos;
  float v[NEXP][8];
  float s[8];
#pragma unroll
  for (int i = 0; i < 8; ++i) s[i] = 0.f;
#pragma unroll
  for (int e = 0; e < NEXP; ++e) {
    float4 v0 = *(const float4*)(We + (size_t)e * DIM * DIM + src);
    float4 v1 = *(const float4*)(We + (size_t)e * DIM * DIM + src + 4);
    v[e][0] = v0.x; v[e][1] = v0.y; v[e][2] = v0.z; v[e][3] = v0.w;
    v[e][4] = v1.x; v[e][5] = v1.y; v[e][6] = v1.z; v[e][7] = v1.w;
#pragma unroll
    for (int i = 0; i < 8; ++i) s[i] += v[e][i];
  }
  size_t chunk = (size_t)frows * DIM;
#pragma unroll
  for (int pp = 0; pp < NPAIR; ++pp) {
    int a = PA[pp], b = PB[pp];
    u16x8 o;
#pragma unroll
    for (int i = 0; i < 8; ++i) o[i] = f2b(s[i] - v[a][i] - v[b][i]);
    *(u16x8*)(Wp + (size_t)pp * chunk + pos) = o;
  }
}

// Pair-bucket GEMM: out rows = gathered x . Wpair[p]^T + biasPair.
// 128x128 tile, BK=64, 16x16x32 bf16 MFMA, global_load_lds w=16, XOR swizzle.
// With NR=2 chunking the Wpair chunk (118 MB) is LLC-resident -> B staging
// is LLC-hit. slot->(p,m0) via precomputed table (no per-block search).
__global__ __launch_bounds__(256, 4) void gemm_pair(
    const unsigned short* __restrict__ A, const unsigned short* __restrict__ Wp,
    const int* __restrict__ cnt, const int* __restrict__ list,
    const int* __restrict__ meta, const int* __restrict__ slotP,
    const int* __restrict__ slotM0, const float* __restrict__ biasPair,
    float* __restrict__ out, int fbase, int frows) {
  __shared__ unsigned short sA[128 * 64];
  __shared__ unsigned short sB[128 * 64];
  __shared__ int sRows[128];
  int slot = blockIdx.y;
  if (slot >= meta[0]) return;
  int ft = blockIdx.x;
  int p = slotP[slot];
  int m0 = slotM0[slot];
  int c = cnt[p];

  int t = threadIdx.x;
  int w = t >> 6, l = t & 63;
  int wm = w & 1, wn = w >> 1;
  int quad = l >> 4, lr = l & 15;
  int cs = (l & 7) ^ ((l >> 3) & 7);

  if (t < 128) {
    int idx = m0 + t;
    if (idx >= c) idx = c - 1;
    sRows[t] = list[p * NTOK + idx];
  }
  __syncthreads();

  size_t rowOffA[4], rowOffB[4];
#pragma unroll
  for (int i = 0; i < 4; ++i)
    rowOffA[i] = (size_t)sRows[i * 32 + w * 8 + (l >> 3)] * DIM;
  const unsigned short* Bb =
      Wp + (size_t)p * frows * DIM + (size_t)ft * 128 * DIM;
#pragma unroll
  for (int i = 0; i < 4; ++i)
    rowOffB[i] = (size_t)(i * 32 + w * 8 + (l >> 3)) * DIM;

  f32x4 acc[4][4];
#pragma unroll
  for (int mi = 0; mi < 4; ++mi)
#pragma unroll
    for (int ni = 0; ni < 4; ++ni) {
      acc[mi][ni][0] = 0.f; acc[mi][ni][1] = 0.f;
      acc[mi][ni][2] = 0.f; acc[mi][ni][3] = 0.f;
    }

  for (int k0 = 0; k0 < DIM; k0 += 64) {
#pragma unroll
    for (int i = 0; i < 4; ++i) {
      __builtin_amdgcn_global_load_lds((GU32*)(A + rowOffA[i] + k0 + cs * 8),
          (LU32*)(sA + (i * 32 + w * 8) * 64), 16, 0, 0);
      __builtin_amdgcn_global_load_lds((GU32*)(Bb + rowOffB[i] + k0 + cs * 8),
          (LU32*)(sB + (i * 32 + w * 8) * 64), 16, 0, 0);
    }
    __syncthreads();
#pragma unroll
    for (int ks = 0; ks < 2; ++ks) {
      bf16x8 aF[4], bF[4];
#pragma unroll
      for (int mi = 0; mi < 4; ++mi)
        aF[mi] = *(const bf16x8*)(sA + (wm * 64 + mi * 16 + lr) * 64 +
                                  (((ks << 2) | quad) ^ (lr & 7)) * 8);
#pragma unroll
      for (int ni = 0; ni < 4; ++ni)
        bF[ni] = *(const bf16x8*)(sB + (wn * 64 + ni * 16 + lr) * 64 +
                                  (((ks << 2) | quad) ^ (lr & 7)) * 8);
#pragma unroll
      for (int mi = 0; mi < 4; ++mi)
#pragma unroll
        for (int ni = 0; ni < 4; ++ni)
          acc[mi][ni] = __builtin_amdgcn_mfma_f32_16x16x32_bf16(aF[mi], bF[ni], acc[mi][ni], 0, 0, 0);
    }
    __syncthreads();
  }

  int f0 = fbase + ft * 128;
  float bb[4];
#pragma unroll
  for (int ni = 0; ni < 4; ++ni)
    bb[ni] = biasPair[p * DIM + f0 + wn * 64 + ni * 16 + lr];
#pragma unroll
  for (int mi = 0; mi < 4; ++mi) {
#pragma unroll
    for (int i = 0; i < 4; ++i) {
      int lrow = wm * 64 + mi * 16 + quad * 4 + i;
      if (m0 + lrow < c) {
        float* orow = out + (size_t)sRows[lrow] * DIM + f0;
#pragma unroll
        for (int ni = 0; ni < 4; ++ni)
          orow[wn * 64 + ni * 16 + lr] = acc[mi][ni][i] + bb[ni];
      }
    }
  }
}

extern "C" void kernel_launch(void* const* d_in, const int* in_sizes, int n_in,
                              void* d_out, int out_size, void* d_ws, size_t ws_size,
                              hipStream_t stream) {
  const float* x  = (const float*)d_in[0];
  const float* Wg = (const float*)d_in[1];
  const float* bg = (const float*)d_in[2];
  const float* We = (const float*)d_in[3];
  const float* be = (const float*)d_in[4];
  float* out = (float*)d_out;

  char* ws = (char*)d_ws;
  unsigned short* xB = (unsigned short*)ws; ws += (size_t)NTOK * DIM * 2;
  int* pid = (int*)ws;          ws += (size_t)NTOK * 4;
  int* cnt = (int*)ws;          ws += 128;
  int* meta = (int*)ws;         ws += 128;
  int* slotP = (int*)ws;        ws += 512;
  int* slotM0 = (int*)ws;       ws += 512;
  int* list = (int*)ws;         ws += (size_t)NPAIR * NTOK * 4;
  float* biasPair = (float*)ws; ws += (size_t)NPAIR * DIM * 4;
  unsigned short* Wp = (unsigned short*)ws;

  // NR=2 deliberately: Wpair chunk (118 MB) stays Infinity-Cache-resident
  // for its gemm round. Grow NR only if workspace is tighter.
  size_t avail = ws_size - (size_t)(ws - (char*)d_ws);
  int NR = 2;
  while (NR < 16 && (size_t)NPAIR * DIM * (size_t)(DIM / NR) * 2 > avail) NR <<= 1;
  int frows = DIM / NR;

  gate_kernel<<<NTOK / 4, 256, 0, stream>>>(x, Wg, bg, xB, pid);
  bucket_kernel<<<2, 1024, 0, stream>>>(pid, be, cnt, meta, slotP, slotM0,
                                        list, biasPair);
  for (int r = 0; r < NR; ++r) {
    int fbase = r * frows;
    pairw_kernel<<<(frows * DIM) / 2048, 256, 0, stream>>>(We, Wp, fbase, frows);
    gemm_pair<<<dim3(frows / 128, SLOTS), 256, 0, stream>>>(
        xB, Wp, cnt, list, meta, slotP, slotM0, biasPair, out, fbase, frows);
  }
}

// Round 5
// 459.340 us; speedup vs baseline: 1.3124x; 1.0052x over previous
//
#include <hip/hip_runtime.h>
#include <hip/hip_bf16.h>
#include <stdint.h>

#define DIM 2048
#define NEXP 8
#define NTOK 8192
#define KSEL 6
#define NPAIR 28
#define SLOTS 92   // max sum of ceil(cnt_p/128) = 64 + 27, +1 safety

typedef short bf16x8 __attribute__((ext_vector_type(8)));
typedef unsigned short u16x8 __attribute__((ext_vector_type(8)));
typedef float f32x4 __attribute__((ext_vector_type(4)));
typedef const __attribute__((address_space(1))) unsigned int GU32;
typedef __attribute__((address_space(3))) unsigned int LU32;

// pair id p <-> (a,b), a<b: p = a*(15-a)/2 + (b-a-1)
static constexpr int PA[NPAIR] = {0,0,0,0,0,0,0,1,1,1,1,1,1,2,2,2,2,2,3,3,3,3,4,4,4,5,5,6};
static constexpr int PB[NPAIR] = {1,2,3,4,5,6,7,2,3,4,5,6,7,3,4,5,6,7,4,5,6,7,5,6,7,6,7,7};

__device__ __forceinline__ unsigned short f2b(float f) {
  union { float f; uint32_t u; } v; v.f = f;
  return (unsigned short)((v.u + 0x7fffu + ((v.u >> 16) & 1u)) >> 16);
}

// Fused independent front-end. Blocks [0, pairwBlocks): Wpair construction
// (streaming, the long pole — scheduled first). Blocks [pairwBlocks, +2048):
// gate (one wave per token, exact fp32 top-k, bf16 x cast, pair id).
// Fusing removes a launch gap and lets gate ride on spare CUs.
__global__ __launch_bounds__(256) void gatepair_kernel(
    const float* __restrict__ x, const float* __restrict__ Wg,
    const float* __restrict__ bg, const float* __restrict__ We,
    unsigned short* __restrict__ xB, int* __restrict__ pid,
    unsigned short* __restrict__ Wp, int fbase, int frows, int pairwBlocks) {
  int bid = blockIdx.x;
  int t = threadIdx.x;
  if (bid < pairwBlocks) {
    // ---- pairw: Wp[p] = bf16(sum_e We[e] - We[a] - We[b]) ----
    size_t pos = ((size_t)bid * 256 + t) * 8;
    size_t src = (size_t)fbase * DIM + pos;
    float v[NEXP][8];
    float s[8];
#pragma unroll
    for (int i = 0; i < 8; ++i) s[i] = 0.f;
#pragma unroll
    for (int e = 0; e < NEXP; ++e) {
      float4 v0 = *(const float4*)(We + (size_t)e * DIM * DIM + src);
      float4 v1 = *(const float4*)(We + (size_t)e * DIM * DIM + src + 4);
      v[e][0] = v0.x; v[e][1] = v0.y; v[e][2] = v0.z; v[e][3] = v0.w;
      v[e][4] = v1.x; v[e][5] = v1.y; v[e][6] = v1.z; v[e][7] = v1.w;
#pragma unroll
      for (int i = 0; i < 8; ++i) s[i] += v[e][i];
    }
    size_t chunk = (size_t)frows * DIM;
#pragma unroll
    for (int pp = 0; pp < NPAIR; ++pp) {
      int a = PA[pp], b = PB[pp];
      u16x8 o;
#pragma unroll
      for (int i = 0; i < 8; ++i) o[i] = f2b(s[i] - v[a][i] - v[b][i]);
      *(u16x8*)(Wp + (size_t)pp * chunk + pos) = o;
    }
    return;
  }
  // ---- gate ----
  int w = t >> 6, l = t & 63;
  int n = (bid - pairwBlocks) * 4 + w;
  const float* xr = x + (size_t)n * DIM;
  float xv[32];
#pragma unroll
  for (int j = 0; j < 8; ++j) {
    float4 v = *(const float4*)(xr + 4 * l + 256 * j);
    xv[4 * j + 0] = v.x; xv[4 * j + 1] = v.y;
    xv[4 * j + 2] = v.z; xv[4 * j + 3] = v.w;
  }
  unsigned short* xbr = xB + (size_t)n * DIM;
#pragma unroll
  for (int j = 0; j < 8; ++j) {
    ushort4 o;
    o.x = f2b(xv[4 * j + 0]); o.y = f2b(xv[4 * j + 1]);
    o.z = f2b(xv[4 * j + 2]); o.w = f2b(xv[4 * j + 3]);
    *(ushort4*)(xbr + 4 * l + 256 * j) = o;
  }
  float sc[NEXP];
#pragma unroll
  for (int e = 0; e < NEXP; ++e) {
    const float* wr = Wg + e * DIM;
    float s = 0.f;
#pragma unroll
    for (int j = 0; j < 8; ++j) {
      float4 v = *(const float4*)(wr + 4 * l + 256 * j);
      s += xv[4 * j + 0] * v.x + xv[4 * j + 1] * v.y +
           xv[4 * j + 2] * v.z + xv[4 * j + 3] * v.w;
    }
#pragma unroll
    for (int off = 32; off > 0; off >>= 1) s += __shfl_xor(s, off, 64);
    sc[e] = s + bg[e];
  }
  if (l == 0) {
    int ex0 = -1, ex1 = -1;
#pragma unroll
    for (int e = 0; e < NEXP; ++e) {
      int rank = 0;
#pragma unroll
      for (int j = 0; j < NEXP; ++j)
        rank += (sc[j] > sc[e]) || (sc[j] == sc[e] && j < e);
      if (rank >= KSEL) { if (ex0 < 0) ex0 = e; else if (ex1 < 0) ex1 = e; }
    }
    pid[n] = ex0 * (15 - ex0) / 2 + (ex1 - ex0 - 1);
  }
}

// Standalone pairw for rounds >= 1 (only used if workspace forces NR > 1).
__global__ __launch_bounds__(256) void pairw_kernel(
    const float* __restrict__ We, unsigned short* __restrict__ Wp,
    int fbase, int frows) {
  size_t pos = ((size_t)blockIdx.x * 256 + threadIdx.x) * 8;
  size_t src = (size_t)fbase * DIM + pos;
  float v[NEXP][8];
  float s[8];
#pragma unroll
  for (int i = 0; i < 8; ++i) s[i] = 0.f;
#pragma unroll
  for (int e = 0; e < NEXP; ++e) {
    float4 v0 = *(const float4*)(We + (size_t)e * DIM * DIM + src);
    float4 v1 = *(const float4*)(We + (size_t)e * DIM * DIM + src + 4);
    v[e][0] = v0.x; v[e][1] = v0.y; v[e][2] = v0.z; v[e][3] = v0.w;
    v[e][4] = v1.x; v[e][5] = v1.y; v[e][6] = v1.z; v[e][7] = v1.w;
#pragma unroll
    for (int i = 0; i < 8; ++i) s[i] += v[e][i];
  }
  size_t chunk = (size_t)frows * DIM;
#pragma unroll
  for (int pp = 0; pp < NPAIR; ++pp) {
    int a = PA[pp], b = PB[pp];
    u16x8 o;
#pragma unroll
    for (int i = 0; i < 8; ++i) o[i] = f2b(s[i] - v[a][i] - v[b][i]);
    *(u16x8*)(Wp + (size_t)pp * chunk + pos) = o;
  }
}

// Block 0: histogram (LDS atomics) -> cnt + slot->(p,m0) table -> scatter.
// Block 1: biasPair. One launch replaces three; no global atomics.
__global__ __launch_bounds__(1024) void bucket_kernel(
    const int* __restrict__ pid, const float* __restrict__ be,
    int* __restrict__ cnt, int* __restrict__ meta,
    int* __restrict__ slotP, int* __restrict__ slotM0,
    int* __restrict__ list, float* __restrict__ biasPair) {
  int t = threadIdx.x;
  if (blockIdx.x == 1) {
#pragma unroll
    for (int it = 0; it < 2; ++it) {
      int f = t + 1024 * it;
      float v[NEXP]; float s = 0.f;
#pragma unroll
      for (int e = 0; e < NEXP; ++e) { v[e] = be[e * DIM + f]; s += v[e]; }
#pragma unroll
      for (int pp = 0; pp < NPAIR; ++pp)
        biasPair[pp * DIM + f] = s - v[PA[pp]] - v[PB[pp]];
    }
    return;
  }
  __shared__ int lcnt[NPAIR];
  __shared__ int lpos[NPAIR];
  if (t < NPAIR) { lcnt[t] = 0; lpos[t] = 0; }
  __syncthreads();
  int p[8];
#pragma unroll
  for (int j = 0; j < 8; ++j) {
    p[j] = pid[t + 1024 * j];
    atomicAdd(&lcnt[p[j]], 1);
  }
  __syncthreads();
  if (t == 0) {
    int ts = 0;
    for (int q = 0; q < NPAIR; ++q) {
      cnt[q] = lcnt[q];
      for (int s0 = 0; s0 < lcnt[q]; s0 += 128) {
        slotP[ts] = q; slotM0[ts] = s0; ++ts;
      }
    }
    meta[0] = ts;
  }
  __syncthreads();
#pragma unroll
  for (int j = 0; j < 8; ++j) {
    int pos = atomicAdd(&lpos[p[j]], 1);
    list[p[j] * NTOK + pos] = t + 1024 * j;
  }
}

// Pair-bucket GEMM: out rows = gathered x . Wpair[p]^T + biasPair.
// 128x128 tile, BK=64, 16x16x32 bf16 MFMA, global_load_lds w=16, XOR swizzle.
// Reversed slot order (freshest Wpair pages first). Waves whose 64-row half
// is fully past c skip frag-loads + MFMA (barriers/staging untouched).
__global__ __launch_bounds__(256, 4) void gemm_pair(
    const unsigned short* __restrict__ A, const unsigned short* __restrict__ Wp,
    const int* __restrict__ cnt, const int* __restrict__ list,
    const int* __restrict__ meta, const int* __restrict__ slotP,
    const int* __restrict__ slotM0, const float* __restrict__ biasPair,
    float* __restrict__ out, int fbase, int frows) {
  __shared__ unsigned short sA[128 * 64];
  __shared__ unsigned short sB[128 * 64];
  __shared__ int sRows[128];
  int total = meta[0];
  if (blockIdx.y >= total) return;
  int slot = total - 1 - blockIdx.y;   // reversed for LLC freshness
  int ft = blockIdx.x;
  int p = slotP[slot];
  int m0 = slotM0[slot];
  int c = cnt[p];

  int t = threadIdx.x;
  int w = t >> 6, l = t & 63;
  int wm = w & 1, wn = w >> 1;
  int quad = l >> 4, lr = l & 15;
  int cs = (l & 7) ^ ((l >> 3) & 7);
  bool live = (wm == 0) || (m0 + 64 < c);   // wm=1 half-tile fully past c?

  if (t < 128) {
    int idx = m0 + t;
    if (idx >= c) idx = c - 1;
    sRows[t] = list[p * NTOK + idx];
  }
  __syncthreads();

  size_t rowOffA[4], rowOffB[4];
#pragma unroll
  for (int i = 0; i < 4; ++i)
    rowOffA[i] = (size_t)sRows[i * 32 + w * 8 + (l >> 3)] * DIM;
  const unsigned short* Bb =
      Wp + (size_t)p * frows * DIM + (size_t)ft * 128 * DIM;
#pragma unroll
  for (int i = 0; i < 4; ++i)
    rowOffB[i] = (size_t)(i * 32 + w * 8 + (l >> 3)) * DIM;

  f32x4 acc[4][4];
#pragma unroll
  for (int mi = 0; mi < 4; ++mi)
#pragma unroll
    for (int ni = 0; ni < 4; ++ni) {
      acc[mi][ni][0] = 0.f; acc[mi][ni][1] = 0.f;
      acc[mi][ni][2] = 0.f; acc[mi][ni][3] = 0.f;
    }

  for (int k0 = 0; k0 < DIM; k0 += 64) {
#pragma unroll
    for (int i = 0; i < 4; ++i) {
      __builtin_amdgcn_global_load_lds((GU32*)(A + rowOffA[i] + k0 + cs * 8),
          (LU32*)(sA + (i * 32 + w * 8) * 64), 16, 0, 0);
      __builtin_amdgcn_global_load_lds((GU32*)(Bb + rowOffB[i] + k0 + cs * 8),
          (LU32*)(sB + (i * 32 + w * 8) * 64), 16, 0, 0);
    }
    __syncthreads();
    if (live) {
#pragma unroll
      for (int ks = 0; ks < 2; ++ks) {
        bf16x8 aF[4], bF[4];
#pragma unroll
        for (int mi = 0; mi < 4; ++mi)
          aF[mi] = *(const bf16x8*)(sA + (wm * 64 + mi * 16 + lr) * 64 +
                                    (((ks << 2) | quad) ^ (lr & 7)) * 8);
#pragma unroll
        for (int ni = 0; ni < 4; ++ni)
          bF[ni] = *(const bf16x8*)(sB + (wn * 64 + ni * 16 + lr) * 64 +
                                    (((ks << 2) | quad) ^ (lr & 7)) * 8);
#pragma unroll
        for (int mi = 0; mi < 4; ++mi)
#pragma unroll
          for (int ni = 0; ni < 4; ++ni)
            acc[mi][ni] = __builtin_amdgcn_mfma_f32_16x16x32_bf16(aF[mi], bF[ni], acc[mi][ni], 0, 0, 0);
      }
    }
    __syncthreads();
  }

  if (!live) return;
  int f0 = fbase + ft * 128;
  float bb[4];
#pragma unroll
  for (int ni = 0; ni < 4; ++ni)
    bb[ni] = biasPair[p * DIM + f0 + wn * 64 + ni * 16 + lr];
#pragma unroll
  for (int mi = 0; mi < 4; ++mi) {
#pragma unroll
    for (int i = 0; i < 4; ++i) {
      int lrow = wm * 64 + mi * 16 + quad * 4 + i;
      if (m0 + lrow < c) {
        float* orow = out + (size_t)sRows[lrow] * DIM + f0;
#pragma unroll
        for (int ni = 0; ni < 4; ++ni)
          orow[wn * 64 + ni * 16 + lr] = acc[mi][ni][i] + bb[ni];
      }
    }
  }
}

extern "C" void kernel_launch(void* const* d_in, const int* in_sizes, int n_in,
                              void* d_out, int out_size, void* d_ws, size_t ws_size,
                              hipStream_t stream) {
  const float* x  = (const float*)d_in[0];
  const float* Wg = (const float*)d_in[1];
  const float* bg = (const float*)d_in[2];
  const float* We = (const float*)d_in[3];
  const float* be = (const float*)d_in[4];
  float* out = (float*)d_out;

  char* ws = (char*)d_ws;
  unsigned short* xB = (unsigned short*)ws; ws += (size_t)NTOK * DIM * 2;
  int* pid = (int*)ws;          ws += (size_t)NTOK * 4;
  int* cnt = (int*)ws;          ws += 128;
  int* meta = (int*)ws;         ws += 128;
  int* slotP = (int*)ws;        ws += 512;
  int* slotM0 = (int*)ws;       ws += 512;
  int* list = (int*)ws;         ws += (size_t)NPAIR * NTOK * 4;
  float* biasPair = (float*)ws; ws += (size_t)NPAIR * DIM * 4;
  unsigned short* Wp = (unsigned short*)ws;

  // NR=1 (full Wpair, 235 MB) when workspace permits; chunk only if forced.
  size_t avail = ws_size - (size_t)(ws - (char*)d_ws);
  int NR = 1;
  while (NR < 16 && (size_t)NPAIR * DIM * (size_t)(DIM / NR) * 2 > avail) NR <<= 1;
  int frows = DIM / NR;

  int pairwBlocks = (frows * DIM) / 2048;
  gatepair_kernel<<<pairwBlocks + NTOK / 4, 256, 0, stream>>>(
      x, Wg, bg, We, xB, pid, Wp, 0, frows, pairwBlocks);
  bucket_kernel<<<2, 1024, 0, stream>>>(pid, be, cnt, meta, slotP, slotM0,
                                        list, biasPair);
  gemm_pair<<<dim3(frows / 128, SLOTS), 256, 0, stream>>>(
      xB, Wp, cnt, list, meta, slotP, slotM0, biasPair, out, 0, frows);
  for (int r = 1; r < NR; ++r) {
    int fbase = r * frows;
    pairw_kernel<<<(frows * DIM) / 2048, 256, 0, stream>>>(We, Wp, fbase, frows);
    gemm_pair<<<dim3(frows / 128, SLOTS), 256, 0, stream>>>(
        xB, Wp, cnt, list, meta, slotP, slotM0, biasPair, out, fbase, frows);
  }
}

// Round 6
// 456.774 us; speedup vs baseline: 1.3198x; 1.0056x over previous
//
#include <hip/hip_runtime.h>
#include <hip/hip_bf16.h>
#include <stdint.h>

#define DIM 2048
#define NEXP 8
#define NTOK 8192
#define KSEL 6
#define NPAIR 28
#define SLOTS 92   // max sum of ceil(cnt_p/128) = 64 + 27, +1 safety

typedef short bf16x8 __attribute__((ext_vector_type(8)));
typedef unsigned short u16x8 __attribute__((ext_vector_type(8)));
typedef float f32x4 __attribute__((ext_vector_type(4)));
typedef const __attribute__((address_space(1))) unsigned int GU32;
typedef __attribute__((address_space(3))) unsigned int LU32;

// pair id p <-> (a,b), a<b: p = a*(15-a)/2 + (b-a-1)
static constexpr int PA[NPAIR] = {0,0,0,0,0,0,0,1,1,1,1,1,1,2,2,2,2,2,3,3,3,3,4,4,4,5,5,6};
static constexpr int PB[NPAIR] = {1,2,3,4,5,6,7,2,3,4,5,6,7,3,4,5,6,7,4,5,6,7,5,6,7,6,7,7};

__device__ __forceinline__ unsigned short f2b(float f) {
  union { float f; uint32_t u; } v; v.f = f;
  return (unsigned short)((v.u + 0x7fffu + ((v.u >> 16) & 1u)) >> 16);
}

// Fused independent front-end. Blocks [0, pairwBlocks): Wpair construction
// (streaming long pole, scheduled first). Blocks [pairwBlocks, +2048): gate.
__global__ __launch_bounds__(256) void gatepair_kernel(
    const float* __restrict__ x, const float* __restrict__ Wg,
    const float* __restrict__ bg, const float* __restrict__ We,
    unsigned short* __restrict__ xB, int* __restrict__ pid,
    unsigned short* __restrict__ Wp, int fbase, int frows, int pairwBlocks) {
  int bid = blockIdx.x;
  int t = threadIdx.x;
  if (bid < pairwBlocks) {
    // ---- pairw: Wp[p] = bf16(sum_e We[e] - We[a] - We[b]) ----
    size_t pos = ((size_t)bid * 256 + t) * 8;
    size_t src = (size_t)fbase * DIM + pos;
    float v[NEXP][8];
    float s[8];
#pragma unroll
    for (int i = 0; i < 8; ++i) s[i] = 0.f;
#pragma unroll
    for (int e = 0; e < NEXP; ++e) {
      float4 v0 = *(const float4*)(We + (size_t)e * DIM * DIM + src);
      float4 v1 = *(const float4*)(We + (size_t)e * DIM * DIM + src + 4);
      v[e][0] = v0.x; v[e][1] = v0.y; v[e][2] = v0.z; v[e][3] = v0.w;
      v[e][4] = v1.x; v[e][5] = v1.y; v[e][6] = v1.z; v[e][7] = v1.w;
#pragma unroll
      for (int i = 0; i < 8; ++i) s[i] += v[e][i];
    }
    size_t chunk = (size_t)frows * DIM;
#pragma unroll
    for (int pp = 0; pp < NPAIR; ++pp) {
      int a = PA[pp], b = PB[pp];
      u16x8 o;
#pragma unroll
      for (int i = 0; i < 8; ++i) o[i] = f2b(s[i] - v[a][i] - v[b][i]);
      *(u16x8*)(Wp + (size_t)pp * chunk + pos) = o;
    }
    return;
  }
  // ---- gate ----
  int w = t >> 6, l = t & 63;
  int n = (bid - pairwBlocks) * 4 + w;
  const float* xr = x + (size_t)n * DIM;
  float xv[32];
#pragma unroll
  for (int j = 0; j < 8; ++j) {
    float4 v = *(const float4*)(xr + 4 * l + 256 * j);
    xv[4 * j + 0] = v.x; xv[4 * j + 1] = v.y;
    xv[4 * j + 2] = v.z; xv[4 * j + 3] = v.w;
  }
  unsigned short* xbr = xB + (size_t)n * DIM;
#pragma unroll
  for (int j = 0; j < 8; ++j) {
    ushort4 o;
    o.x = f2b(xv[4 * j + 0]); o.y = f2b(xv[4 * j + 1]);
    o.z = f2b(xv[4 * j + 2]); o.w = f2b(xv[4 * j + 3]);
    *(ushort4*)(xbr + 4 * l + 256 * j) = o;
  }
  float sc[NEXP];
#pragma unroll
  for (int e = 0; e < NEXP; ++e) {
    const float* wr = Wg + e * DIM;
    float s = 0.f;
#pragma unroll
    for (int j = 0; j < 8; ++j) {
      float4 v = *(const float4*)(wr + 4 * l + 256 * j);
      s += xv[4 * j + 0] * v.x + xv[4 * j + 1] * v.y +
           xv[4 * j + 2] * v.z + xv[4 * j + 3] * v.w;
    }
#pragma unroll
    for (int off = 32; off > 0; off >>= 1) s += __shfl_xor(s, off, 64);
    sc[e] = s + bg[e];
  }
  if (l == 0) {
    int ex0 = -1, ex1 = -1;
#pragma unroll
    for (int e = 0; e < NEXP; ++e) {
      int rank = 0;
#pragma unroll
      for (int j = 0; j < NEXP; ++j)
        rank += (sc[j] > sc[e]) || (sc[j] == sc[e] && j < e);
      if (rank >= KSEL) { if (ex0 < 0) ex0 = e; else if (ex1 < 0) ex1 = e; }
    }
    pid[n] = ex0 * (15 - ex0) / 2 + (ex1 - ex0 - 1);
  }
}

// Standalone pairw (only used if workspace forces NR > 1).
__global__ __launch_bounds__(256) void pairw_kernel(
    const float* __restrict__ We, unsigned short* __restrict__ Wp,
    int fbase, int frows) {
  size_t pos = ((size_t)blockIdx.x * 256 + threadIdx.x) * 8;
  size_t src = (size_t)fbase * DIM + pos;
  float v[NEXP][8];
  float s[8];
#pragma unroll
  for (int i = 0; i < 8; ++i) s[i] = 0.f;
#pragma unroll
  for (int e = 0; e < NEXP; ++e) {
    float4 v0 = *(const float4*)(We + (size_t)e * DIM * DIM + src);
    float4 v1 = *(const float4*)(We + (size_t)e * DIM * DIM + src + 4);
    v[e][0] = v0.x; v[e][1] = v0.y; v[e][2] = v0.z; v[e][3] = v0.w;
    v[e][4] = v1.x; v[e][5] = v1.y; v[e][6] = v1.z; v[e][7] = v1.w;
#pragma unroll
    for (int i = 0; i < 8; ++i) s[i] += v[e][i];
  }
  size_t chunk = (size_t)frows * DIM;
#pragma unroll
  for (int pp = 0; pp < NPAIR; ++pp) {
    int a = PA[pp], b = PB[pp];
    u16x8 o;
#pragma unroll
    for (int i = 0; i < 8; ++i) o[i] = f2b(s[i] - v[a][i] - v[b][i]);
    *(u16x8*)(Wp + (size_t)pp * chunk + pos) = o;
  }
}

// Block 0: histogram (LDS atomics) -> cnt + slot->(p,m0) table -> scatter.
// Block 1: biasPair. No global atomics.
__global__ __launch_bounds__(1024) void bucket_kernel(
    const int* __restrict__ pid, const float* __restrict__ be,
    int* __restrict__ cnt, int* __restrict__ meta,
    int* __restrict__ slotP, int* __restrict__ slotM0,
    int* __restrict__ list, float* __restrict__ biasPair) {
  int t = threadIdx.x;
  if (blockIdx.x == 1) {
#pragma unroll
    for (int it = 0; it < 2; ++it) {
      int f = t + 1024 * it;
      float v[NEXP]; float s = 0.f;
#pragma unroll
      for (int e = 0; e < NEXP; ++e) { v[e] = be[e * DIM + f]; s += v[e]; }
#pragma unroll
      for (int pp = 0; pp < NPAIR; ++pp)
        biasPair[pp * DIM + f] = s - v[PA[pp]] - v[PB[pp]];
    }
    return;
  }
  __shared__ int lcnt[NPAIR];
  __shared__ int lpos[NPAIR];
  if (t < NPAIR) { lcnt[t] = 0; lpos[t] = 0; }
  __syncthreads();
  int p[8];
#pragma unroll
  for (int j = 0; j < 8; ++j) {
    p[j] = pid[t + 1024 * j];
    atomicAdd(&lcnt[p[j]], 1);
  }
  __syncthreads();
  if (t == 0) {
    int ts = 0;
    for (int q = 0; q < NPAIR; ++q) {
      cnt[q] = lcnt[q];
      for (int s0 = 0; s0 < lcnt[q]; s0 += 128) {
        slotP[ts] = q; slotM0[ts] = s0; ++ts;
      }
    }
    meta[0] = ts;
  }
  __syncthreads();
#pragma unroll
  for (int j = 0; j < 8; ++j) {
    int pos = atomicAdd(&lpos[p[j]], 1);
    list[p[j] * NTOK + pos] = t + 1024 * j;
  }
}

// Pair-bucket GEMM, 128(M)x256(N) tile, 8 waves (2x4), BK=64, single-buffer
// LDS (48.5 KB -> 2 blocks/CU with 124 regs/wave), 16x16x32 bf16 MFMA,
// global_load_lds w=16, XOR bank swizzle. Same 2-barrier sync structure as
// the verified 128x128 kernel — only geometry changed. 25% fewer staged
// bytes per MFMA; half the blocks; grid-x=8 keeps B-sharing blocks
// (same p,ft, adjacent slots; linear stride 8) on one XCD.
__global__ __launch_bounds__(512, 4) void gemm_pair(
    const unsigned short* __restrict__ A, const unsigned short* __restrict__ Wp,
    const int* __restrict__ cnt, const int* __restrict__ list,
    const int* __restrict__ meta, const int* __restrict__ slotP,
    const int* __restrict__ slotM0, const float* __restrict__ biasPair,
    float* __restrict__ out, int fbase, int frows) {
  __shared__ unsigned short sA[128 * 64];
  __shared__ unsigned short sB[256 * 64];
  __shared__ int sRows[128];
  int total = meta[0];
  if (blockIdx.y >= total) return;
  int slot = total - 1 - blockIdx.y;   // reversed for LLC freshness
  int ft = blockIdx.x;
  int p = slotP[slot];
  int m0 = slotM0[slot];
  int c = cnt[p];

  int t = threadIdx.x;
  int w = t >> 6, l = t & 63;          // w in 0..7
  int wm = w >> 2, wn = w & 3;         // 2 (M) x 4 (N) wave grid
  int quad = l >> 4, lr = l & 15;
  int cs = (l & 7) ^ ((l >> 3) & 7);
  bool live = (wm == 0) || (m0 + 64 < c);  // dead M-half skip

  if (t < 128) {
    int idx = m0 + t;
    if (idx >= c) idx = c - 1;
    sRows[t] = list[p * NTOK + idx];
  }
  __syncthreads();

  size_t rowOffA[2], rowOffB[4];
#pragma unroll
  for (int i = 0; i < 2; ++i)
    rowOffA[i] = (size_t)sRows[i * 64 + w * 8 + (l >> 3)] * DIM;
  const unsigned short* Bb =
      Wp + (size_t)p * frows * DIM + (size_t)ft * 256 * DIM;
#pragma unroll
  for (int i = 0; i < 4; ++i)
    rowOffB[i] = (size_t)(i * 64 + w * 8 + (l >> 3)) * DIM;

  f32x4 acc[4][4];
#pragma unroll
  for (int mi = 0; mi < 4; ++mi)
#pragma unroll
    for (int ni = 0; ni < 4; ++ni) {
      acc[mi][ni][0] = 0.f; acc[mi][ni][1] = 0.f;
      acc[mi][ni][2] = 0.f; acc[mi][ni][3] = 0.f;
    }

  for (int k0 = 0; k0 < DIM; k0 += 64) {
#pragma unroll
    for (int i = 0; i < 2; ++i)
      __builtin_amdgcn_global_load_lds((GU32*)(A + rowOffA[i] + k0 + cs * 8),
          (LU32*)(sA + (i * 64 + w * 8) * 64), 16, 0, 0);
#pragma unroll
    for (int i = 0; i < 4; ++i)
      __builtin_amdgcn_global_load_lds((GU32*)(Bb + rowOffB[i] + k0 + cs * 8),
          (LU32*)(sB + (i * 64 + w * 8) * 64), 16, 0, 0);
    __syncthreads();
    if (live) {
#pragma unroll
      for (int ks = 0; ks < 2; ++ks) {
        bf16x8 aF[4], bF[4];
#pragma unroll
        for (int mi = 0; mi < 4; ++mi)
          aF[mi] = *(const bf16x8*)(sA + (wm * 64 + mi * 16 + lr) * 64 +
                                    (((ks << 2) | quad) ^ (lr & 7)) * 8);
#pragma unroll
        for (int ni = 0; ni < 4; ++ni)
          bF[ni] = *(const bf16x8*)(sB + (wn * 64 + ni * 16 + lr) * 64 +
                                    (((ks << 2) | quad) ^ (lr & 7)) * 8);
#pragma unroll
        for (int mi = 0; mi < 4; ++mi)
#pragma unroll
          for (int ni = 0; ni < 4; ++ni)
            acc[mi][ni] = __builtin_amdgcn_mfma_f32_16x16x32_bf16(aF[mi], bF[ni], acc[mi][ni], 0, 0, 0);
      }
    }
    __syncthreads();
  }

  if (!live) return;
  int f0 = fbase + ft * 256;
  float bb[4];
#pragma unroll
  for (int ni = 0; ni < 4; ++ni)
    bb[ni] = biasPair[p * DIM + f0 + wn * 64 + ni * 16 + lr];
#pragma unroll
  for (int mi = 0; mi < 4; ++mi) {
#pragma unroll
    for (int i = 0; i < 4; ++i) {
      int lrow = wm * 64 + mi * 16 + quad * 4 + i;
      if (m0 + lrow < c) {
        float* orow = out + (size_t)sRows[lrow] * DIM + f0;
#pragma unroll
        for (int ni = 0; ni < 4; ++ni)
          orow[wn * 64 + ni * 16 + lr] = acc[mi][ni][i] + bb[ni];
      }
    }
  }
}

extern "C" void kernel_launch(void* const* d_in, const int* in_sizes, int n_in,
                              void* d_out, int out_size, void* d_ws, size_t ws_size,
                              hipStream_t stream) {
  const float* x  = (const float*)d_in[0];
  const float* Wg = (const float*)d_in[1];
  const float* bg = (const float*)d_in[2];
  const float* We = (const float*)d_in[3];
  const float* be = (const float*)d_in[4];
  float* out = (float*)d_out;

  char* ws = (char*)d_ws;
  unsigned short* xB = (unsigned short*)ws; ws += (size_t)NTOK * DIM * 2;
  int* pid = (int*)ws;          ws += (size_t)NTOK * 4;
  int* cnt = (int*)ws;          ws += 128;
  int* meta = (int*)ws;         ws += 128;
  int* slotP = (int*)ws;        ws += 512;
  int* slotM0 = (int*)ws;       ws += 512;
  int* list = (int*)ws;         ws += (size_t)NPAIR * NTOK * 4;
  float* biasPair = (float*)ws; ws += (size_t)NPAIR * DIM * 4;
  unsigned short* Wp = (unsigned short*)ws;

  // NR=1 (full Wpair, 235 MB) when workspace permits; chunk only if forced.
  // frows must stay a multiple of 256 (gemm BN) -> NR <= 8.
  size_t avail = ws_size - (size_t)(ws - (char*)d_ws);
  int NR = 1;
  while (NR < 8 && (size_t)NPAIR * DIM * (size_t)(DIM / NR) * 2 > avail) NR <<= 1;
  int frows = DIM / NR;

  int pairwBlocks = (frows * DIM) / 2048;
  gatepair_kernel<<<pairwBlocks + NTOK / 4, 256, 0, stream>>>(
      x, Wg, bg, We, xB, pid, Wp, 0, frows, pairwBlocks);
  bucket_kernel<<<2, 1024, 0, stream>>>(pid, be, cnt, meta, slotP, slotM0,
                                        list, biasPair);
  gemm_pair<<<dim3(frows / 256, SLOTS), 512, 0, stream>>>(
      xB, Wp, cnt, list, meta, slotP, slotM0, biasPair, out, 0, frows);
  for (int r = 1; r < NR; ++r) {
    int fbase = r * frows;
    pairw_kernel<<<(frows * DIM) / 2048, 256, 0, stream>>>(We, Wp, fbase, frows);
    gemm_pair<<<dim3(frows / 256, SLOTS), 512, 0, stream>>>(
        xB, Wp, cnt, list, meta, slotP, slotM0, biasPair, out, fbase, frows);
  }
}